// Round 1
// baseline (489.303 us; speedup 1.0000x reference)
//
#include <hip/hip_runtime.h>
#include <math.h>

#define NB    (1 << 20)
#define HH    512
#define WW    1024
#define RANK  16
#define FC    128

__global__ __launch_bounds__(256) void bg_render_kernel(
    const float* __restrict__ viewdirs,
    const float* __restrict__ bg_mat,
    const float* __restrict__ W1,
    const float* __restrict__ W2,
    float* __restrict__ out)
{
    // LDS-staged weights: W1 transposed to [j][k] so per-j reads are 4x ds_read_b128
    // (wave-uniform address -> broadcast, bank-conflict-free).
    __shared__ float sW1t[FC][RANK];  // 8 KB
    __shared__ float sW2[FC][4];      // 2 KB, padded 3->4 for float4 reads

    const int tid = threadIdx.x;
    for (int t = tid; t < RANK * FC; t += 256) {
        int k = t / FC, j = t % FC;        // W1 is [RANK][FC] row-major
        sW1t[j][k] = W1[t];
    }
    for (int t = tid; t < FC * 4; t += 256) {
        int j = t >> 2, c = t & 3;
        sW2[j][c] = (c < 3) ? W2[j * 3 + c] : 0.0f;
    }
    __syncthreads();

    const int i = blockIdx.x * 256 + tid;  // NB divisible by grid*block exactly

    const float dx = viewdirs[3 * i + 0];
    const float dy = viewdirs[3 * i + 1];
    const float dz = viewdirs[3 * i + 2];

    // equirect unwrap
    const float INV_PI = 0.31830988618379067154f;
    float phi   = atan2f(dy, dx);
    float theta = acosf(fminf(fmaxf(dz, -1.0f), 1.0f));
    float gx = phi * INV_PI;
    float gy = theta * (2.0f * INV_PI) - 1.0f;

    // bilinear setup (matches reference arithmetic order)
    float ix = (gx + 1.0f) * (0.5f * (float)WW) - 0.5f;
    float iy = (gy + 1.0f) * (0.5f * (float)HH) - 0.5f;
    float x0f = floorf(ix), y0f = floorf(iy);
    float wx1 = ix - x0f, wx0 = 1.0f - wx1;
    float wy1 = iy - y0f, wy0 = 1.0f - wy1;
    int x0 = (int)x0f, y0 = (int)y0f;
    int x1 = x0 + 1,   y1 = y0 + 1;

    float w00 = wx0 * wy0, w10 = wx1 * wy0, w01 = wx0 * wy1, w11 = wx1 * wy1;
    // fold validity into weights (== reference's v*valid then *w)
    bool vx0 = (x0 >= 0) & (x0 <= WW - 1);
    bool vx1 = (x1 >= 0) & (x1 <= WW - 1);
    bool vy0 = (y0 >= 0) & (y0 <= HH - 1);
    bool vy1 = (y1 >= 0) & (y1 <= HH - 1);
    if (!(vx0 & vy0)) w00 = 0.0f;
    if (!(vx1 & vy0)) w10 = 0.0f;
    if (!(vx0 & vy1)) w01 = 0.0f;
    if (!(vx1 & vy1)) w11 = 0.0f;

    int cx0 = min(max(x0, 0), WW - 1), cx1 = min(max(x1, 0), WW - 1);
    int cy0 = min(max(y0, 0), HH - 1), cy1 = min(max(y1, 0), HH - 1);
    int b00 = cy0 * WW + cx0, b10 = cy0 * WW + cx1;
    int b01 = cy1 * WW + cx0, b11 = cy1 * WW + cx1;

    // gather 16-channel embedding (scattered loads; bg_mat fits in L2/L3)
    float emb[RANK];
    #pragma unroll
    for (int c = 0; c < RANK; ++c) {
        const float* img = bg_mat + c * (HH * WW);
        emb[c] = img[b00] * w00 + img[b10] * w10 + img[b01] * w01 + img[b11] * w11;
    }

    // fused MLP: h_j = relu(emb . W1[:,j]); out_c += h_j * W2[j,c]
    float a0 = 0.0f, a1 = 0.0f, a2 = 0.0f;
    #pragma unroll 8
    for (int j = 0; j < FC; ++j) {
        const float4* w1v = (const float4*)&sW1t[j][0];
        float hj = 0.0f;
        #pragma unroll
        for (int q = 0; q < 4; ++q) {
            float4 w = w1v[q];
            hj = fmaf(emb[4 * q + 0], w.x, hj);
            hj = fmaf(emb[4 * q + 1], w.y, hj);
            hj = fmaf(emb[4 * q + 2], w.z, hj);
            hj = fmaf(emb[4 * q + 3], w.w, hj);
        }
        hj = fmaxf(hj, 0.0f);
        float4 w2 = *(const float4*)&sW2[j][0];
        a0 = fmaf(hj, w2.x, a0);
        a1 = fmaf(hj, w2.y, a1);
        a2 = fmaf(hj, w2.z, a2);
    }

    // softplus, numerically stable (== log1p(exp(x)))
    float o0 = fmaxf(a0, 0.0f) + log1pf(expf(-fabsf(a0)));
    float o1 = fmaxf(a1, 0.0f) + log1pf(expf(-fabsf(a1)));
    float o2 = fmaxf(a2, 0.0f) + log1pf(expf(-fabsf(a2)));

    out[3 * i + 0] = o0;
    out[3 * i + 1] = o1;
    out[3 * i + 2] = o2;
}

extern "C" void kernel_launch(void* const* d_in, const int* in_sizes, int n_in,
                              void* d_out, int out_size, void* d_ws, size_t ws_size,
                              hipStream_t stream) {
    const float* viewdirs = (const float*)d_in[0];
    // d_in[1] = roughness: unused by the reference
    const float* bg_mat   = (const float*)d_in[2];
    const float* W1       = (const float*)d_in[3];
    const float* W2       = (const float*)d_in[4];
    float* out            = (float*)d_out;

    bg_render_kernel<<<dim3(NB / 256), dim3(256), 0, stream>>>(
        viewdirs, bg_mat, W1, W2, out);
}

// Round 2
// 123.841 us; speedup vs baseline: 3.9511x; 3.9511x over previous
//
#include <hip/hip_runtime.h>
#include <math.h>

#define NB    (1 << 20)
#define HH    512
#define WW    1024
#define RANK  16
#define FC    128
#define HW    (HH * WW)

// ---------------------------------------------------------------------------
// Pre-pass: transpose planar bg_mat [16][H][W] -> channel-interleaved
// tex [H*W][16] so one bilinear tap = one 64B cache line.
// Reads are coalesced (16 stride-1 sweeps), writes are 64B/thread contiguous.
// ---------------------------------------------------------------------------
__global__ __launch_bounds__(256) void transpose_kernel(
    const float* __restrict__ bg, float* __restrict__ tex)
{
    const int t = blockIdx.x * 256 + threadIdx.x;   // texel index, HW % 256 == 0
    float4 v[4];
    #pragma unroll
    for (int q = 0; q < 4; ++q) {
        v[q].x = bg[(4 * q + 0) * HW + t];
        v[q].y = bg[(4 * q + 1) * HW + t];
        v[q].z = bg[(4 * q + 2) * HW + t];
        v[q].w = bg[(4 * q + 3) * HW + t];
    }
    float4* dst = (float4*)(tex + (size_t)t * 16);
    dst[0] = v[0]; dst[1] = v[1]; dst[2] = v[2]; dst[3] = v[3];
}

// ---------------------------------------------------------------------------
// Main fused kernel. MODE 0: gather from interleaved tex (fast path).
//                    MODE 1: gather from planar bg_mat (ws too small fallback).
// ---------------------------------------------------------------------------
template <int MODE>
__global__ __launch_bounds__(256) void bg_render_kernel(
    const float* __restrict__ viewdirs,
    const float* __restrict__ src,      // MODE 0: tex [HW][16]; MODE 1: planar bg_mat
    const float* __restrict__ W1,
    const float* __restrict__ W2,
    float* __restrict__ out)
{
    __shared__ float sW1t[FC][RANK];  // W1 transposed: [j][k], uniform ds_read_b128
    __shared__ float sW2[FC][4];      // padded 3->4

    const int tid = threadIdx.x;
    for (int t = tid; t < RANK * FC; t += 256) {
        int k = t / FC, j = t % FC;        // W1 is [RANK][FC] row-major
        sW1t[j][k] = W1[t];
    }
    for (int t = tid; t < FC * 4; t += 256) {
        int j = t >> 2, c = t & 3;
        sW2[j][c] = (c < 3) ? W2[j * 3 + c] : 0.0f;
    }
    __syncthreads();

    const int i = blockIdx.x * 256 + tid;

    const float dx = viewdirs[3 * i + 0];
    const float dy = viewdirs[3 * i + 1];
    const float dz = viewdirs[3 * i + 2];

    // equirect unwrap
    const float INV_PI = 0.31830988618379067154f;
    float phi   = atan2f(dy, dx);
    float theta = acosf(fminf(fmaxf(dz, -1.0f), 1.0f));
    float gx = phi * INV_PI;
    float gy = theta * (2.0f * INV_PI) - 1.0f;

    // bilinear setup (matches reference arithmetic order)
    float ix = (gx + 1.0f) * (0.5f * (float)WW) - 0.5f;
    float iy = (gy + 1.0f) * (0.5f * (float)HH) - 0.5f;
    float x0f = floorf(ix), y0f = floorf(iy);
    float wx1 = ix - x0f, wx0 = 1.0f - wx1;
    float wy1 = iy - y0f, wy0 = 1.0f - wy1;
    int x0 = (int)x0f, y0 = (int)y0f;
    int x1 = x0 + 1,   y1 = y0 + 1;

    float w00 = wx0 * wy0, w10 = wx1 * wy0, w01 = wx0 * wy1, w11 = wx1 * wy1;
    bool vx0 = (x0 >= 0) & (x0 <= WW - 1);
    bool vx1 = (x1 >= 0) & (x1 <= WW - 1);
    bool vy0 = (y0 >= 0) & (y0 <= HH - 1);
    bool vy1 = (y1 >= 0) & (y1 <= HH - 1);
    if (!(vx0 & vy0)) w00 = 0.0f;
    if (!(vx1 & vy0)) w10 = 0.0f;
    if (!(vx0 & vy1)) w01 = 0.0f;
    if (!(vx1 & vy1)) w11 = 0.0f;

    int cx0 = min(max(x0, 0), WW - 1), cx1 = min(max(x1, 0), WW - 1);
    int cy0 = min(max(y0, 0), HH - 1), cy1 = min(max(y1, 0), HH - 1);
    int b00 = cy0 * WW + cx0, b10 = cy0 * WW + cx1;
    int b01 = cy1 * WW + cx0, b11 = cy1 * WW + cx1;

    float emb[RANK];
    if (MODE == 0) {
        // one tap = one 64B line: 4x global_load_dwordx4
        const float4* t00 = (const float4*)(src + (size_t)b00 * 16);
        const float4* t10 = (const float4*)(src + (size_t)b10 * 16);
        const float4* t01 = (const float4*)(src + (size_t)b01 * 16);
        const float4* t11 = (const float4*)(src + (size_t)b11 * 16);
        #pragma unroll
        for (int q = 0; q < 4; ++q) {
            float4 a = t00[q], b = t10[q], c = t01[q], d = t11[q];
            emb[4 * q + 0] = a.x * w00 + b.x * w10 + c.x * w01 + d.x * w11;
            emb[4 * q + 1] = a.y * w00 + b.y * w10 + c.y * w01 + d.y * w11;
            emb[4 * q + 2] = a.z * w00 + b.z * w10 + c.z * w01 + d.z * w11;
            emb[4 * q + 3] = a.w * w00 + b.w * w10 + c.w * w01 + d.w * w11;
        }
    } else {
        #pragma unroll
        for (int c = 0; c < RANK; ++c) {
            const float* img = src + c * HW;
            emb[c] = img[b00] * w00 + img[b10] * w10 + img[b01] * w01 + img[b11] * w11;
        }
    }

    // fused MLP: h_j = relu(emb . W1[:,j]); out_c += h_j * W2[j,c]
    float a0 = 0.0f, a1 = 0.0f, a2 = 0.0f;
    #pragma unroll 8
    for (int j = 0; j < FC; ++j) {
        const float4* w1v = (const float4*)&sW1t[j][0];
        float hj = 0.0f;
        #pragma unroll
        for (int q = 0; q < 4; ++q) {
            float4 w = w1v[q];
            hj = fmaf(emb[4 * q + 0], w.x, hj);
            hj = fmaf(emb[4 * q + 1], w.y, hj);
            hj = fmaf(emb[4 * q + 2], w.z, hj);
            hj = fmaf(emb[4 * q + 3], w.w, hj);
        }
        hj = fmaxf(hj, 0.0f);
        float4 w2 = *(const float4*)&sW2[j][0];
        a0 = fmaf(hj, w2.x, a0);
        a1 = fmaf(hj, w2.y, a1);
        a2 = fmaf(hj, w2.z, a2);
    }

    float o0 = fmaxf(a0, 0.0f) + log1pf(expf(-fabsf(a0)));
    float o1 = fmaxf(a1, 0.0f) + log1pf(expf(-fabsf(a1)));
    float o2 = fmaxf(a2, 0.0f) + log1pf(expf(-fabsf(a2)));

    out[3 * i + 0] = o0;
    out[3 * i + 1] = o1;
    out[3 * i + 2] = o2;
}

extern "C" void kernel_launch(void* const* d_in, const int* in_sizes, int n_in,
                              void* d_out, int out_size, void* d_ws, size_t ws_size,
                              hipStream_t stream) {
    const float* viewdirs = (const float*)d_in[0];
    // d_in[1] = roughness: unused by the reference
    const float* bg_mat   = (const float*)d_in[2];
    const float* W1       = (const float*)d_in[3];
    const float* W2       = (const float*)d_in[4];
    float* out            = (float*)d_out;

    const size_t tex_bytes = (size_t)HW * RANK * sizeof(float);   // 32 MB

    if (ws_size >= tex_bytes) {
        float* tex = (float*)d_ws;
        transpose_kernel<<<dim3(HW / 256), dim3(256), 0, stream>>>(bg_mat, tex);
        bg_render_kernel<0><<<dim3(NB / 256), dim3(256), 0, stream>>>(
            viewdirs, tex, W1, W2, out);
    } else {
        bg_render_kernel<1><<<dim3(NB / 256), dim3(256), 0, stream>>>(
            viewdirs, bg_mat, W1, W2, out);
    }
}

// Round 3
// 100.541 us; speedup vs baseline: 4.8667x; 1.2317x over previous
//
#include <hip/hip_runtime.h>
#include <hip/hip_bf16.h>
#include <math.h>

#define NB    (1 << 20)
#define HH    512
#define WW    1024
#define RANK  16
#define FC    128
#define HW    (HH * WW)
#define TPB   256
#define ITERS 4

typedef float f32x16 __attribute__((ext_vector_type(16)));
typedef short bf16x8 __attribute__((ext_vector_type(8)));

__device__ __forceinline__ short f2bf(float f) {
    __hip_bfloat16 b = __float2bfloat16(f);   // RNE
    return *reinterpret_cast<short*>(&b);
}

// ---------------------------------------------------------------------------
// Pre-pass: planar bg_mat [16][H][W] -> interleaved tex [H*W][16]
// (one bilinear tap = one 64B cache line)
// ---------------------------------------------------------------------------
__global__ __launch_bounds__(256) void transpose_kernel(
    const float* __restrict__ bg, float* __restrict__ tex)
{
    const int t = blockIdx.x * 256 + threadIdx.x;
    float4 v[4];
    #pragma unroll
    for (int q = 0; q < 4; ++q) {
        v[q].x = bg[(4 * q + 0) * HW + t];
        v[q].y = bg[(4 * q + 1) * HW + t];
        v[q].z = bg[(4 * q + 2) * HW + t];
        v[q].w = bg[(4 * q + 3) * HW + t];
    }
    float4* dst = (float4*)(tex + (size_t)t * 16);
    dst[0] = v[0]; dst[1] = v[1]; dst[2] = v[2]; dst[3] = v[3];
}

// ---------------------------------------------------------------------------
// Fused render: gather (VALU) -> GEMM1 16->128 (MFMA) -> relu -> GEMM2
// 128->3 (MFMA, K-axis permuted so GEMM1's C-layout IS GEMM2's B-layout)
// MODE 0: interleaved tex; MODE 1: planar bg_mat fallback.
// ---------------------------------------------------------------------------
template <int MODE>
__global__ __launch_bounds__(TPB) void bg_render_mfma(
    const float* __restrict__ viewdirs,
    const float* __restrict__ src,
    const float* __restrict__ W1,      // [16][128] row-major
    const float* __restrict__ W2,      // [128][3] row-major
    float* __restrict__ out)
{
    __shared__ __align__(16) unsigned short emb_lds[2][TPB][RANK];  // bf16 bits, 16 KB

    const int tid  = threadIdx.x;
    const int lane = tid & 63;
    const int wid  = tid >> 6;
    const int l31  = lane & 31;
    const int q5   = lane >> 5;

    const f32x16 kZero = {0.f,0.f,0.f,0.f,0.f,0.f,0.f,0.f,
                          0.f,0.f,0.f,0.f,0.f,0.f,0.f,0.f};

    // ---- GEMM1 A-fragments: A[row=j_local][k] = W1[k][32*jt + j_local] ----
    // lane: row = l31, k = 8*q5 + i  (K=16 exact for 32x32x16)
    bf16x8 w1f[4];
    #pragma unroll
    for (int jt = 0; jt < 4; ++jt) {
        bf16x8 v;
        #pragma unroll
        for (int i = 0; i < 8; ++i) {
            const int k = 8 * q5 + i;
            v[i] = f2bf(W1[k * FC + 32 * jt + l31]);
        }
        w1f[jt] = v;
    }

    // ---- GEMM2 A-fragments with permuted K: neuron n = 16*kt+8*(i>>2)+4*q5+(i&3)
    // rows 0-2 hold W2 cols 0-2; rows 4-6 duplicate them (epilogue symmetry).
    bf16x8 w2f[8];
    {
        const int  c   = l31;
        const bool ok  = ((c & 3) < 3) && (c < 8);
        const int  c3  = c & 3;
        #pragma unroll
        for (int kt = 0; kt < 8; ++kt) {
            bf16x8 v;
            #pragma unroll
            for (int i = 0; i < 8; ++i) {
                const int n = 16 * kt + 8 * (i >> 2) + 4 * q5 + (i & 3);
                v[i] = ok ? f2bf(W2[3 * n + c3]) : (short)0;
            }
            w2f[kt] = v;
        }
    }

    const int block_base = blockIdx.x * (TPB * ITERS);

    for (int it = 0; it < ITERS; ++it) {
        const int buf = it & 1;
        const int i   = block_base + it * TPB + tid;   // this thread's sample

        // ---- equirect unwrap (identical math to reference) ----
        const float dx = viewdirs[3 * i + 0];
        const float dy = viewdirs[3 * i + 1];
        const float dz = viewdirs[3 * i + 2];
        const float INV_PI = 0.31830988618379067154f;
        float phi   = atan2f(dy, dx);
        float theta = acosf(fminf(fmaxf(dz, -1.0f), 1.0f));
        float gx = phi * INV_PI;
        float gy = theta * (2.0f * INV_PI) - 1.0f;

        float ix = (gx + 1.0f) * (0.5f * (float)WW) - 0.5f;
        float iy = (gy + 1.0f) * (0.5f * (float)HH) - 0.5f;
        float x0f = floorf(ix), y0f = floorf(iy);
        float wx1 = ix - x0f, wx0 = 1.0f - wx1;
        float wy1 = iy - y0f, wy0 = 1.0f - wy1;
        int x0 = (int)x0f, y0 = (int)y0f;
        int x1 = x0 + 1,   y1 = y0 + 1;

        float w00 = wx0 * wy0, w10 = wx1 * wy0, w01 = wx0 * wy1, w11 = wx1 * wy1;
        bool vx0 = (x0 >= 0) & (x0 <= WW - 1);
        bool vx1 = (x1 >= 0) & (x1 <= WW - 1);
        bool vy0 = (y0 >= 0) & (y0 <= HH - 1);
        bool vy1 = (y1 >= 0) & (y1 <= HH - 1);
        if (!(vx0 & vy0)) w00 = 0.0f;
        if (!(vx1 & vy0)) w10 = 0.0f;
        if (!(vx0 & vy1)) w01 = 0.0f;
        if (!(vx1 & vy1)) w11 = 0.0f;

        int cx0 = min(max(x0, 0), WW - 1), cx1 = min(max(x1, 0), WW - 1);
        int cy0 = min(max(y0, 0), HH - 1), cy1 = min(max(y1, 0), HH - 1);
        int b00 = cy0 * WW + cx0, b10 = cy0 * WW + cx1;
        int b01 = cy1 * WW + cx0, b11 = cy1 * WW + cx1;

        float emb[RANK];
        if (MODE == 0) {
            const float4* t00 = (const float4*)(src + (size_t)b00 * 16);
            const float4* t10 = (const float4*)(src + (size_t)b10 * 16);
            const float4* t01 = (const float4*)(src + (size_t)b01 * 16);
            const float4* t11 = (const float4*)(src + (size_t)b11 * 16);
            #pragma unroll
            for (int q = 0; q < 4; ++q) {
                float4 a = t00[q], b = t10[q], c = t01[q], d = t11[q];
                emb[4 * q + 0] = a.x * w00 + b.x * w10 + c.x * w01 + d.x * w11;
                emb[4 * q + 1] = a.y * w00 + b.y * w10 + c.y * w01 + d.y * w11;
                emb[4 * q + 2] = a.z * w00 + b.z * w10 + c.z * w01 + d.z * w11;
                emb[4 * q + 3] = a.w * w00 + b.w * w10 + c.w * w01 + d.w * w11;
            }
        } else {
            #pragma unroll
            for (int ch = 0; ch < RANK; ++ch) {
                const float* img = src + ch * HW;
                emb[ch] = img[b00] * w00 + img[b10] * w10
                        + img[b01] * w01 + img[b11] * w11;
            }
        }

        // ---- stage bf16 emb to LDS (B-fragment layout: row=sample, 16 k) ----
        {
            bf16x8 v0, v1;
            #pragma unroll
            for (int k = 0; k < 8; ++k) { v0[k] = f2bf(emb[k]); v1[k] = f2bf(emb[8 + k]); }
            *(bf16x8*)&emb_lds[buf][tid][0] = v0;
            *(bf16x8*)&emb_lds[buf][tid][8] = v1;
        }
        __syncthreads();

        // ---- MFMA pipeline: 2 groups x (4x GEMM1 + 8x GEMM2) ----
        f32x16 acc2[2] = {kZero, kZero};
        #pragma unroll
        for (int g = 0; g < 2; ++g) {
            const int row = wid * 64 + g * 32 + l31;
            const bf16x8 b1 = *(const bf16x8*)&emb_lds[buf][row][q5 * 8];
            #pragma unroll
            for (int jt = 0; jt < 4; ++jt) {
                f32x16 acc1 = __builtin_amdgcn_mfma_f32_32x32x16_bf16(
                    w1f[jt], b1, kZero, 0, 0, 0);
                bf16x8 plo, phi_;
                #pragma unroll
                for (int r = 0; r < 8; ++r) {
                    plo[r]  = f2bf(fmaxf(acc1[r],     0.0f));
                    phi_[r] = f2bf(fmaxf(acc1[8 + r], 0.0f));
                }
                acc2[g] = __builtin_amdgcn_mfma_f32_32x32x16_bf16(
                    w2f[2 * jt],     plo,  acc2[g], 0, 0, 0);
                acc2[g] = __builtin_amdgcn_mfma_f32_32x32x16_bf16(
                    w2f[2 * jt + 1], phi_, acc2[g], 0, 0, 0);
            }
        }

        // ---- epilogue: thread i owns sample i (q5 picks its group's acc) ----
        float a0 = q5 ? acc2[1][0] : acc2[0][0];
        float a1 = q5 ? acc2[1][1] : acc2[0][1];
        float a2 = q5 ? acc2[1][2] : acc2[0][2];

        float o0 = fmaxf(a0, 0.0f) + log1pf(expf(-fabsf(a0)));
        float o1 = fmaxf(a1, 0.0f) + log1pf(expf(-fabsf(a1)));
        float o2 = fmaxf(a2, 0.0f) + log1pf(expf(-fabsf(a2)));

        out[3 * i + 0] = o0;
        out[3 * i + 1] = o1;
        out[3 * i + 2] = o2;
    }
}

extern "C" void kernel_launch(void* const* d_in, const int* in_sizes, int n_in,
                              void* d_out, int out_size, void* d_ws, size_t ws_size,
                              hipStream_t stream) {
    const float* viewdirs = (const float*)d_in[0];
    // d_in[1] = roughness: unused by the reference
    const float* bg_mat   = (const float*)d_in[2];
    const float* W1       = (const float*)d_in[3];
    const float* W2       = (const float*)d_in[4];
    float* out            = (float*)d_out;

    const size_t tex_bytes = (size_t)HW * RANK * sizeof(float);   // 32 MB
    const int nblocks = NB / (TPB * ITERS);

    if (ws_size >= tex_bytes) {
        float* tex = (float*)d_ws;
        transpose_kernel<<<dim3(HW / 256), dim3(256), 0, stream>>>(bg_mat, tex);
        bg_render_mfma<0><<<dim3(nblocks), dim3(TPB), 0, stream>>>(
            viewdirs, tex, W1, W2, out);
    } else {
        bg_render_mfma<1><<<dim3(nblocks), dim3(TPB), 0, stream>>>(
            viewdirs, bg_mat, W1, W2, out);
    }
}

// Round 4
// 97.036 us; speedup vs baseline: 5.0425x; 1.0361x over previous
//
#include <hip/hip_runtime.h>
#include <hip/hip_bf16.h>
#include <math.h>

#define NB    (1 << 20)
#define HH    512
#define WW    1024
#define RANK  16
#define FC    128
#define HW    (HH * WW)
#define TPB   256
#define ITERS 2

typedef float f32x16 __attribute__((ext_vector_type(16)));
typedef short bf16x8 __attribute__((ext_vector_type(8)));
typedef unsigned int uint2v __attribute__((ext_vector_type(2)));

__device__ __forceinline__ short f2bf(float f) {
    __hip_bfloat16 b = __float2bfloat16(f);   // RNE
    return *reinterpret_cast<short*>(&b);
}

// ---------------------------------------------------------------------------
// Pre-pass: planar bg_mat [16][H][W] -> interleaved tex [H*W][16]
// (one bilinear tap = one 64B cache line)
// ---------------------------------------------------------------------------
__global__ __launch_bounds__(256) void transpose_kernel(
    const float* __restrict__ bg, float* __restrict__ tex)
{
    const int t = blockIdx.x * 256 + threadIdx.x;
    float4 v[4];
    #pragma unroll
    for (int q = 0; q < 4; ++q) {
        v[q].x = bg[(4 * q + 0) * HW + t];
        v[q].y = bg[(4 * q + 1) * HW + t];
        v[q].z = bg[(4 * q + 2) * HW + t];
        v[q].w = bg[(4 * q + 3) * HW + t];
    }
    float4* dst = (float4*)(tex + (size_t)t * 16);
    dst[0] = v[0]; dst[1] = v[1]; dst[2] = v[2]; dst[3] = v[3];
}

// ---------------------------------------------------------------------------
// Fused render, barrier-free: gather (VALU) -> permlane32_swap wave transpose
// -> GEMM1 16->128 (MFMA) -> relu -> GEMM2 128->3 (MFMA, K-permuted so
// GEMM1's C-layout IS GEMM2's B-layout). No LDS, no __syncthreads.
// ---------------------------------------------------------------------------
template <int MODE>
__global__ __launch_bounds__(TPB) void bg_render_mfma(
    const float* __restrict__ viewdirs,
    const float* __restrict__ src,     // MODE 0: tex [HW][16]; MODE 1: planar
    const float* __restrict__ W1,      // [16][128] row-major
    const float* __restrict__ W2,      // [128][3] row-major
    float* __restrict__ out)
{
    const int tid  = threadIdx.x;
    const int lane = tid & 63;
    const int l31  = lane & 31;
    const int q5   = lane >> 5;

    const f32x16 kZero = {0.f,0.f,0.f,0.f,0.f,0.f,0.f,0.f,
                          0.f,0.f,0.f,0.f,0.f,0.f,0.f,0.f};

    // ---- GEMM1 A-fragments: A[row=j_local][k] = W1[k][32*jt + j_local] ----
    bf16x8 w1f[4];
    #pragma unroll
    for (int jt = 0; jt < 4; ++jt) {
        bf16x8 v;
        #pragma unroll
        for (int i = 0; i < 8; ++i) {
            const int k = 8 * q5 + i;
            v[i] = f2bf(W1[k * FC + 32 * jt + l31]);
        }
        w1f[jt] = v;
    }

    // ---- GEMM2 A-fragments, K-permuted: neuron n = 16*kt+8*(i>>2)+4*q5+(i&3)
    // rows 0-2 = W2 cols; rows 4-6 duplicate them so both lane-halves see all 3.
    bf16x8 w2f[8];
    {
        const int  c   = l31;
        const bool ok  = ((c & 3) < 3) && (c < 8);
        const int  c3  = c & 3;
        #pragma unroll
        for (int kt = 0; kt < 8; ++kt) {
            bf16x8 v;
            #pragma unroll
            for (int i = 0; i < 8; ++i) {
                const int n = 16 * kt + 8 * (i >> 2) + 4 * q5 + (i & 3);
                v[i] = ok ? f2bf(W2[3 * n + c3]) : (short)0;
            }
            w2f[kt] = v;
        }
    }

    const int block_base = blockIdx.x * (TPB * ITERS);

    #pragma unroll 1
    for (int it = 0; it < ITERS; ++it) {
        const int i = block_base + it * TPB + tid;   // this thread's sample

        // ---- equirect unwrap (identical math to reference) ----
        const float dx = viewdirs[3 * i + 0];
        const float dy = viewdirs[3 * i + 1];
        const float dz = viewdirs[3 * i + 2];
        const float INV_PI = 0.31830988618379067154f;
        float phi   = atan2f(dy, dx);
        float theta = acosf(fminf(fmaxf(dz, -1.0f), 1.0f));
        float gx = phi * INV_PI;
        float gy = theta * (2.0f * INV_PI) - 1.0f;

        float ix = (gx + 1.0f) * (0.5f * (float)WW) - 0.5f;
        float iy = (gy + 1.0f) * (0.5f * (float)HH) - 0.5f;
        float x0f = floorf(ix), y0f = floorf(iy);
        float wx1 = ix - x0f, wx0 = 1.0f - wx1;
        float wy1 = iy - y0f, wy0 = 1.0f - wy1;
        int x0 = (int)x0f, y0 = (int)y0f;
        int x1 = x0 + 1,   y1 = y0 + 1;

        float w00 = wx0 * wy0, w10 = wx1 * wy0, w01 = wx0 * wy1, w11 = wx1 * wy1;
        bool vx0 = (x0 >= 0) & (x0 <= WW - 1);
        bool vx1 = (x1 >= 0) & (x1 <= WW - 1);
        bool vy0 = (y0 >= 0) & (y0 <= HH - 1);
        bool vy1 = (y1 >= 0) & (y1 <= HH - 1);
        if (!(vx0 & vy0)) w00 = 0.0f;
        if (!(vx1 & vy0)) w10 = 0.0f;
        if (!(vx0 & vy1)) w01 = 0.0f;
        if (!(vx1 & vy1)) w11 = 0.0f;

        int cx0 = min(max(x0, 0), WW - 1), cx1 = min(max(x1, 0), WW - 1);
        int cy0 = min(max(y0, 0), HH - 1), cy1 = min(max(y1, 0), HH - 1);
        int b00 = cy0 * WW + cx0, b10 = cy0 * WW + cx1;
        int b01 = cy1 * WW + cx0, b11 = cy1 * WW + cx1;

        float emb[RANK];
        if (MODE == 0) {
            const float4* t00 = (const float4*)(src + (size_t)b00 * 16);
            const float4* t10 = (const float4*)(src + (size_t)b10 * 16);
            const float4* t01 = (const float4*)(src + (size_t)b01 * 16);
            const float4* t11 = (const float4*)(src + (size_t)b11 * 16);
            #pragma unroll
            for (int q = 0; q < 4; ++q) {
                float4 a = t00[q], b = t10[q], c = t01[q], d = t11[q];
                emb[4 * q + 0] = a.x * w00 + b.x * w10 + c.x * w01 + d.x * w11;
                emb[4 * q + 1] = a.y * w00 + b.y * w10 + c.y * w01 + d.y * w11;
                emb[4 * q + 2] = a.z * w00 + b.z * w10 + c.z * w01 + d.z * w11;
                emb[4 * q + 3] = a.w * w00 + b.w * w10 + c.w * w01 + d.w * w11;
            }
        } else {
            #pragma unroll
            for (int ch = 0; ch < RANK; ++ch) {
                const float* img = src + ch * HW;
                emb[ch] = img[b00] * w00 + img[b10] * w10
                        + img[b01] * w01 + img[b11] * w11;
            }
        }

        // ---- wave-local transpose: build BOTH groups' B-fragments with 4
        // permlane32_swap. e_lo[d]={k=2d,2d+1} of own sample; after
        // {a',b'}=swap(e_lo,e_hi): a' = group0 frag, b' = group1 frag.
        union { bf16x8 v; unsigned int u[4]; } elo, ehi, bg0, bg1;
        #pragma unroll
        for (int k = 0; k < 8; ++k) {
            elo.v[k] = f2bf(emb[k]);
            ehi.v[k] = f2bf(emb[8 + k]);
        }
        #pragma unroll
        for (int d = 0; d < 4; ++d) {
            uint2v r = __builtin_amdgcn_permlane32_swap(elo.u[d], ehi.u[d], false, false);
            bg0.u[d] = r.x;
            bg1.u[d] = r.y;
        }

        // ---- MFMA pipeline: 2 groups x (4x GEMM1 + 8x GEMM2) ----
        f32x16 acc2[2] = {kZero, kZero};
        #pragma unroll
        for (int g = 0; g < 2; ++g) {
            const bf16x8 b1 = g ? bg1.v : bg0.v;
            #pragma unroll
            for (int jt = 0; jt < 4; ++jt) {
                f32x16 acc1 = __builtin_amdgcn_mfma_f32_32x32x16_bf16(
                    w1f[jt], b1, kZero, 0, 0, 0);
                bf16x8 plo, phi_;
                #pragma unroll
                for (int r = 0; r < 8; ++r) {
                    plo[r]  = f2bf(fmaxf(acc1[r],     0.0f));
                    phi_[r] = f2bf(fmaxf(acc1[8 + r], 0.0f));
                }
                acc2[g] = __builtin_amdgcn_mfma_f32_32x32x16_bf16(
                    w2f[2 * jt],     plo,  acc2[g], 0, 0, 0);
                acc2[g] = __builtin_amdgcn_mfma_f32_32x32x16_bf16(
                    w2f[2 * jt + 1], phi_, acc2[g], 0, 0, 0);
            }
        }

        // ---- epilogue: thread's sample = lane; q5 picks its group's acc ----
        float a0 = q5 ? acc2[1][0] : acc2[0][0];
        float a1 = q5 ? acc2[1][1] : acc2[0][1];
        float a2 = q5 ? acc2[1][2] : acc2[0][2];

        float o0 = fmaxf(a0, 0.0f) + log1pf(expf(-fabsf(a0)));
        float o1 = fmaxf(a1, 0.0f) + log1pf(expf(-fabsf(a1)));
        float o2 = fmaxf(a2, 0.0f) + log1pf(expf(-fabsf(a2)));

        out[3 * i + 0] = o0;
        out[3 * i + 1] = o1;
        out[3 * i + 2] = o2;
    }
}

extern "C" void kernel_launch(void* const* d_in, const int* in_sizes, int n_in,
                              void* d_out, int out_size, void* d_ws, size_t ws_size,
                              hipStream_t stream) {
    const float* viewdirs = (const float*)d_in[0];
    // d_in[1] = roughness: unused by the reference
    const float* bg_mat   = (const float*)d_in[2];
    const float* W1       = (const float*)d_in[3];
    const float* W2       = (const float*)d_in[4];
    float* out            = (float*)d_out;

    const size_t tex_bytes = (size_t)HW * RANK * sizeof(float);   // 32 MB
    const int nblocks = NB / (TPB * ITERS);

    if (ws_size >= tex_bytes) {
        float* tex = (float*)d_ws;
        transpose_kernel<<<dim3(HW / 256), dim3(256), 0, stream>>>(bg_mat, tex);
        bg_render_mfma<0><<<dim3(nblocks), dim3(TPB), 0, stream>>>(
            viewdirs, tex, W1, W2, out);
    } else {
        bg_render_mfma<1><<<dim3(nblocks), dim3(TPB), 0, stream>>>(
            viewdirs, bg_mat, W1, W2, out);
    }
}

// Round 5
// 90.708 us; speedup vs baseline: 5.3943x; 1.0698x over previous
//
#include <hip/hip_runtime.h>
#include <hip/hip_bf16.h>
#include <hip/hip_fp16.h>
#include <math.h>

#define NB    (1 << 20)
#define HH    512
#define WW    1024
#define RANK  16
#define FC    128
#define HW    (HH * WW)
#define TPB   256

typedef float f32x16 __attribute__((ext_vector_type(16)));
typedef short bf16x8 __attribute__((ext_vector_type(8)));
typedef unsigned int uint2v __attribute__((ext_vector_type(2)));

__device__ __forceinline__ short f2bf(float f) {
    __hip_bfloat16 b = __float2bfloat16(f);   // RNE
    return *reinterpret_cast<short*>(&b);
}

// ---------------------------------------------------------------------------
// Pre-pass: planar bg_mat [16][H][W] fp32 -> interleaved f16 tex [H*W][16]
// (one bilinear tap = one 32B half-line; f16 mantissa(10b) > bf16(7b) used
//  downstream, so this adds no visible error)
// ---------------------------------------------------------------------------
__global__ __launch_bounds__(256) void transpose_f16_kernel(
    const float* __restrict__ bg, __half* __restrict__ tex)
{
    const int t = blockIdx.x * 256 + threadIdx.x;
    union { unsigned short s[16]; uint4 q[2]; } pk;
    #pragma unroll
    for (int c = 0; c < RANK; ++c) {
        __half h = __float2half_rn(bg[c * HW + t]);
        pk.s[c] = *reinterpret_cast<unsigned short*>(&h);
    }
    uint4* dst = (uint4*)(tex + (size_t)t * 16);
    dst[0] = pk.q[0];
    dst[1] = pk.q[1];
}

struct TapAddr { int b00, b10, b01, b11; float w00, w10, w01, w11; };

// ---------------------------------------------------------------------------
// Fused render, barrier-free + software-pipelined 2 samples/thread.
// gather(f16 tex) -> permlane32_swap wave transpose -> GEMM1 16->128 (MFMA)
// -> relu -> GEMM2 128->3 (MFMA, K-permuted so GEMM1 C-layout == GEMM2
// B-layout). MODE 0: f16 tex; MODE 1: planar f32 fallback.
// ---------------------------------------------------------------------------
template <int MODE>
__global__ __launch_bounds__(TPB) void bg_render_mfma(
    const float* __restrict__ viewdirs,
    const void*  __restrict__ srcv,    // MODE 0: __half tex [HW][16]; MODE 1: float planar
    const float* __restrict__ W1,      // [16][128] row-major
    const float* __restrict__ W2,      // [128][3] row-major
    float* __restrict__ out)
{
    const int tid  = threadIdx.x;
    const int lane = tid & 63;
    const int l31  = lane & 31;
    const int q5   = lane >> 5;

    const f32x16 kZero = {0.f,0.f,0.f,0.f,0.f,0.f,0.f,0.f,
                          0.f,0.f,0.f,0.f,0.f,0.f,0.f,0.f};

    // ---- GEMM1 A-fragments: A[row=j_local][k] = W1[k][32*jt + j_local] ----
    bf16x8 w1f[4];
    #pragma unroll
    for (int jt = 0; jt < 4; ++jt) {
        bf16x8 v;
        #pragma unroll
        for (int i = 0; i < 8; ++i) {
            const int k = 8 * q5 + i;
            v[i] = f2bf(W1[k * FC + 32 * jt + l31]);
        }
        w1f[jt] = v;
    }

    // ---- GEMM2 A-fragments, K-permuted: neuron n = 16*kt+8*(i>>2)+4*q5+(i&3)
    bf16x8 w2f[8];
    {
        const int  c   = l31;
        const bool ok  = ((c & 3) < 3) && (c < 8);
        const int  c3  = c & 3;
        #pragma unroll
        for (int kt = 0; kt < 8; ++kt) {
            bf16x8 v;
            #pragma unroll
            for (int i = 0; i < 8; ++i) {
                const int n = 16 * kt + 8 * (i >> 2) + 4 * q5 + (i & 3);
                v[i] = ok ? f2bf(W2[3 * n + c3]) : (short)0;
            }
            w2f[kt] = v;
        }
    }

    // ---- per-sample address/weight computation (identical math to ref) ----
    auto mkaddr = [&](int i) -> TapAddr {
        const float dx = viewdirs[3 * i + 0];
        const float dy = viewdirs[3 * i + 1];
        const float dz = viewdirs[3 * i + 2];
        const float INV_PI = 0.31830988618379067154f;
        float phi   = atan2f(dy, dx);
        float theta = acosf(fminf(fmaxf(dz, -1.0f), 1.0f));
        float gx = phi * INV_PI;
        float gy = theta * (2.0f * INV_PI) - 1.0f;

        float ix = (gx + 1.0f) * (0.5f * (float)WW) - 0.5f;
        float iy = (gy + 1.0f) * (0.5f * (float)HH) - 0.5f;
        float x0f = floorf(ix), y0f = floorf(iy);
        float wx1 = ix - x0f, wx0 = 1.0f - wx1;
        float wy1 = iy - y0f, wy0 = 1.0f - wy1;
        int x0 = (int)x0f, y0 = (int)y0f;
        int x1 = x0 + 1,   y1 = y0 + 1;

        TapAddr A;
        A.w00 = wx0 * wy0; A.w10 = wx1 * wy0; A.w01 = wx0 * wy1; A.w11 = wx1 * wy1;
        bool vx0 = (x0 >= 0) & (x0 <= WW - 1);
        bool vx1 = (x1 >= 0) & (x1 <= WW - 1);
        bool vy0 = (y0 >= 0) & (y0 <= HH - 1);
        bool vy1 = (y1 >= 0) & (y1 <= HH - 1);
        if (!(vx0 & vy0)) A.w00 = 0.0f;
        if (!(vx1 & vy0)) A.w10 = 0.0f;
        if (!(vx0 & vy1)) A.w01 = 0.0f;
        if (!(vx1 & vy1)) A.w11 = 0.0f;

        int cx0 = min(max(x0, 0), WW - 1), cx1 = min(max(x1, 0), WW - 1);
        int cy0 = min(max(y0, 0), HH - 1), cy1 = min(max(y1, 0), HH - 1);
        A.b00 = cy0 * WW + cx0; A.b10 = cy0 * WW + cx1;
        A.b01 = cy1 * WW + cx0; A.b11 = cy1 * WW + cx1;
        return A;
    };

    // accumulate one f16 tap (8+8 channels in 2 uint4) into emb with weight w
    auto acc_tap = [](float* e, uint4 qa, uint4 qb, float w) {
        const unsigned int u[8] = {qa.x, qa.y, qa.z, qa.w, qb.x, qb.y, qb.z, qb.w};
        #pragma unroll
        for (int d = 0; d < 8; ++d) {
            __half2 h = *reinterpret_cast<const __half2*>(&u[d]);
            float2 f = __half22float2(h);
            e[2 * d + 0] = fmaf(f.x, w, e[2 * d + 0]);
            e[2 * d + 1] = fmaf(f.y, w, e[2 * d + 1]);
        }
    };

    // ---- MFMA + epilogue for one sample's emb[16] ----
    auto mlp = [&](const float* emb, int i) {
        union { bf16x8 v; unsigned int u[4]; } elo, ehi, bq0, bq1;
        #pragma unroll
        for (int k = 0; k < 8; ++k) {
            elo.v[k] = f2bf(emb[k]);
            ehi.v[k] = f2bf(emb[8 + k]);
        }
        #pragma unroll
        for (int d = 0; d < 4; ++d) {
            uint2v r = __builtin_amdgcn_permlane32_swap(elo.u[d], ehi.u[d], false, false);
            bq0.u[d] = r.x;
            bq1.u[d] = r.y;
        }

        f32x16 accA = kZero, accB = kZero;
        #pragma unroll
        for (int jt = 0; jt < 4; ++jt) {
            f32x16 h0 = __builtin_amdgcn_mfma_f32_32x32x16_bf16(w1f[jt], bq0.v, kZero, 0, 0, 0);
            f32x16 h1 = __builtin_amdgcn_mfma_f32_32x32x16_bf16(w1f[jt], bq1.v, kZero, 0, 0, 0);
            bf16x8 p0lo, p0hi, p1lo, p1hi;
            #pragma unroll
            for (int r = 0; r < 8; ++r) {
                p0lo[r] = f2bf(fmaxf(h0[r],     0.0f));
                p0hi[r] = f2bf(fmaxf(h0[8 + r], 0.0f));
                p1lo[r] = f2bf(fmaxf(h1[r],     0.0f));
                p1hi[r] = f2bf(fmaxf(h1[8 + r], 0.0f));
            }
            accA = __builtin_amdgcn_mfma_f32_32x32x16_bf16(w2f[2 * jt],     p0lo, accA, 0, 0, 0);
            accA = __builtin_amdgcn_mfma_f32_32x32x16_bf16(w2f[2 * jt + 1], p0hi, accA, 0, 0, 0);
            accB = __builtin_amdgcn_mfma_f32_32x32x16_bf16(w2f[2 * jt],     p1lo, accB, 0, 0, 0);
            accB = __builtin_amdgcn_mfma_f32_32x32x16_bf16(w2f[2 * jt + 1], p1hi, accB, 0, 0, 0);
        }

        float a0 = q5 ? accB[0] : accA[0];
        float a1 = q5 ? accB[1] : accA[1];
        float a2 = q5 ? accB[2] : accA[2];

        float o0 = fmaxf(a0, 0.0f) + log1pf(expf(-fabsf(a0)));
        float o1 = fmaxf(a1, 0.0f) + log1pf(expf(-fabsf(a1)));
        float o2 = fmaxf(a2, 0.0f) + log1pf(expf(-fabsf(a2)));

        out[3 * i + 0] = o0;
        out[3 * i + 1] = o1;
        out[3 * i + 2] = o2;
    };

    const int i0 = blockIdx.x * (2 * TPB) + tid;
    const int i1 = i0 + TPB;

    if (MODE == 0) {
        const __half* tex = (const __half*)srcv;
        // addresses for both samples first (independent transcendental chains)
        TapAddr A0 = mkaddr(i0);
        TapAddr A1 = mkaddr(i1);

        // issue ALL 16 tap loads (8 per sample) before any consumption
        const uint4* p;
        p = (const uint4*)(tex + (size_t)A0.b00 * 16); uint4 a00a = p[0], a00b = p[1];
        p = (const uint4*)(tex + (size_t)A0.b10 * 16); uint4 a10a = p[0], a10b = p[1];
        p = (const uint4*)(tex + (size_t)A0.b01 * 16); uint4 a01a = p[0], a01b = p[1];
        p = (const uint4*)(tex + (size_t)A0.b11 * 16); uint4 a11a = p[0], a11b = p[1];
        p = (const uint4*)(tex + (size_t)A1.b00 * 16); uint4 b00a = p[0], b00b = p[1];
        p = (const uint4*)(tex + (size_t)A1.b10 * 16); uint4 b10a = p[0], b10b = p[1];
        p = (const uint4*)(tex + (size_t)A1.b01 * 16); uint4 b01a = p[0], b01b = p[1];
        p = (const uint4*)(tex + (size_t)A1.b11 * 16); uint4 b11a = p[0], b11b = p[1];

        // sample 0: blend + MLP (waits only on its own 8 loads; s1's stay in flight)
        {
            float e[RANK];
            #pragma unroll
            for (int c = 0; c < RANK; ++c) e[c] = 0.0f;
            acc_tap(e, a00a, a00b, A0.w00);
            acc_tap(e, a10a, a10b, A0.w10);
            acc_tap(e, a01a, a01b, A0.w01);
            acc_tap(e, a11a, a11b, A0.w11);
            mlp(e, i0);
        }
        // sample 1
        {
            float e[RANK];
            #pragma unroll
            for (int c = 0; c < RANK; ++c) e[c] = 0.0f;
            acc_tap(e, b00a, b00b, A1.w00);
            acc_tap(e, b10a, b10b, A1.w10);
            acc_tap(e, b01a, b01b, A1.w01);
            acc_tap(e, b11a, b11b, A1.w11);
            mlp(e, i1);
        }
    } else {
        const float* src = (const float*)srcv;
        #pragma unroll 1
        for (int s = 0; s < 2; ++s) {
            const int i = s ? i1 : i0;
            TapAddr A = mkaddr(i);
            float e[RANK];
            #pragma unroll
            for (int ch = 0; ch < RANK; ++ch) {
                const float* img = src + ch * HW;
                e[ch] = img[A.b00] * A.w00 + img[A.b10] * A.w10
                      + img[A.b01] * A.w01 + img[A.b11] * A.w11;
            }
            mlp(e, i);
        }
    }
}

extern "C" void kernel_launch(void* const* d_in, const int* in_sizes, int n_in,
                              void* d_out, int out_size, void* d_ws, size_t ws_size,
                              hipStream_t stream) {
    const float* viewdirs = (const float*)d_in[0];
    // d_in[1] = roughness: unused by the reference
    const float* bg_mat   = (const float*)d_in[2];
    const float* W1       = (const float*)d_in[3];
    const float* W2       = (const float*)d_in[4];
    float* out            = (float*)d_out;

    const size_t tex_bytes = (size_t)HW * RANK * sizeof(__half);   // 16 MB
    const int nblocks = NB / (2 * TPB);

    if (ws_size >= tex_bytes) {
        __half* tex = (__half*)d_ws;
        transpose_f16_kernel<<<dim3(HW / 256), dim3(256), 0, stream>>>(bg_mat, tex);
        bg_render_mfma<0><<<dim3(nblocks), dim3(TPB), 0, stream>>>(
            viewdirs, (const void*)tex, W1, W2, out);
    } else {
        bg_render_mfma<1><<<dim3(nblocks), dim3(TPB), 0, stream>>>(
            viewdirs, (const void*)bg_mat, W1, W2, out);
    }
}